// Round 15
// baseline (2670.106 us; speedup 1.0000x reference)
//
#include <hip/hip_runtime.h>
#include <hip/hip_bf16.h>
#include <stdint.h>

#define PI_F     3.14159265358979323846f
#define TWO_PI_F 6.28318530717958647692f
#define INV2PI_F 0.15915494309189535f

typedef __attribute__((ext_vector_type(8))) short bf16x8;
typedef __attribute__((ext_vector_type(4))) float f32x4;

#define BB 64
#define NN 256
#define SS 257
#define DD 512
#define HH 8
#define HDD 64
#define LL 8
#define MTOK 16448
#define MPAD 16512
#define BSTR 264
#define VSTR 320

__device__ __forceinline__ float b2f(unsigned short u){
  union { float f; uint32_t i; } c; c.i = ((uint32_t)u) << 16; return c.f;
}
__device__ __forceinline__ unsigned short f2b(float f){
  union { float f; uint32_t i; } c; c.f = f;
  uint32_t r = c.i + 0x7FFFu + ((c.i >> 16) & 1u);
  return (unsigned short)(r >> 16);
}
// fast gelu (tanh form, exp-based; rcpf for the divide). |err| vs erf-gelu
// ~5e-4, negligible after the *e_w2 (~0.01) contraction and bf16 store.
__device__ __forceinline__ float gelu_fast(float z){
  const float z2 = z*z;
  const float u2 = z * (1.5957691216f + 0.071354816f*z2);
  const float e = __expf(u2);
  const float r = __builtin_amdgcn_rcpf(1.f + e);
  const float th = 1.f - 2.f*r;
  return 0.5f*z*(1.f + th);
}

typedef __attribute__((address_space(1))) unsigned char ga_t;
typedef __attribute__((address_space(3))) unsigned char ls_t;
__device__ __forceinline__ void gl_lds16(const void* g, void* l){
  __builtin_amdgcn_global_load_lds((ga_t*)g, (ls_t*)l, 16, 0, 0);
}

// ---------------- weight f32 -> bf16 ----------------
__global__ __launch_bounds__(256) void cvt_kernel(const float* __restrict__ src,
                                                  unsigned short* __restrict__ dst, int n2){
  int i = blockIdx.x*256 + threadIdx.x;
  int stride = gridDim.x*256;
  for (; i < n2; i += stride){
    float2 v = ((const float2*)src)[i];
    ((uint32_t*)dst)[i] = (uint32_t)f2b(v.x) | ((uint32_t)f2b(v.y) << 16);
  }
}

// ---------------- edge MLP: interior bias + row means ----------------
__global__ __launch_bounds__(256) void edge_kernel(
    const float* __restrict__ x_full, const float* __restrict__ e_w1, const float* __restrict__ e_b1,
    const float* __restrict__ e_w2, const float* __restrict__ e_b2,
    unsigned short* __restrict__ bias, float* __restrict__ central)
{
  const int bi = blockIdx.x;
  const int b = bi >> 8, i = bi & 255;
  const int j = threadIdx.x;
  const float yi = x_full[((long)b*NN + i)*16 + 14];
  const float fi = x_full[((long)b*NN + i)*16 + 15];
  const float yj = x_full[((long)b*NN + j)*16 + 14];
  const float fj = x_full[((long)b*NN + j)*16 + 15];
  const float dy = fabsf(yi - yj);
  const float xw = fi - fj + PI_F;
  const float tw = xw * INV2PI_F;
  const float md = (tw - floorf(tw)) * TWO_PI_F;
  const float dphi = fabsf(md - PI_F);
  const float dr = sqrtf(dy*dy + dphi*dphi + 1e-8f);
  float raw[8];
  #pragma unroll
  for (int hh = 0; hh < 8; ++hh) raw[hh] = e_b2[hh];
  #pragma unroll
  for (int k = 0; k < 16; ++k){
    float z = e_w1[k*3]*dy + e_w1[k*3+1]*dphi + e_w1[k*3+2]*dr + e_b1[k];
    float g = gelu_fast(z);
    #pragma unroll
    for (int hh = 0; hh < 8; ++hh) raw[hh] += g * e_w2[hh*16 + k];
  }
  #pragma unroll
  for (int hh = 0; hh < 8; ++hh)
    bias[(((long)b*HH + hh)*SS + 1 + i)*BSTR + 1 + j] = f2b(raw[hh]);
  #pragma unroll
  for (int m = 1; m < 64; m <<= 1)
    #pragma unroll
    for (int hh = 0; hh < 8; ++hh) raw[hh] += __shfl_xor(raw[hh], m);
  __shared__ float cw[4][8];
  const int wv = j >> 6;
  if ((j & 63) == 0)
    for (int hh = 0; hh < 8; ++hh) cw[wv][hh] = raw[hh];
  __syncthreads();
  if (j < 8){
    float t = cw[0][j] + cw[1][j] + cw[2][j] + cw[3][j];
    central[((long)b*NN + i)*HH + j] = t * (1.f/NN);
  }
}

__global__ __launch_bounds__(256) void edge_border_kernel(
    const float* __restrict__ central, const float* __restrict__ edge_scale,
    unsigned short* __restrict__ bias)
{
  const int bh = blockIdx.x;
  const int b = bh >> 3, h = bh & 7;
  const int j = threadIdx.x;
  const float es = edge_scale[0];
  const float cv = central[((long)b*NN + j)*HH + h] * es;
  const long base = (long)bh*SS*BSTR;
  const unsigned short u = f2b(cv);
  bias[base + 1 + j] = u;                 // row 0 (CLS query)
  bias[base + (long)(1+j)*BSTR] = u;      // col 0 (CLS key)
  if (j == 0) bias[base] = 0;
}

// ---------------- bias repack into MFMA-fragment layout (runs ONCE) --------
// biasT[bh][qt][jt][mi][lane][idx8], idx8 = ni*4+r: each flash lane's 16
// values per jt become two contiguous bf16x8 loads (coalesced, prefetchable).
// OOB rows/cols clamped to valid in-range entries (masked downstream).
__global__ __launch_bounds__(256) void brepack_kernel(
    const unsigned short* __restrict__ biasO, unsigned short* __restrict__ biasT)
{
  const int bh = blockIdx.x;       // 0..511
  const int qt = blockIdx.y;       // 0..8
  const int t = threadIdx.x;
  const int ln = t & 63, wv = t >> 6;
  const int l16 = ln & 15, lhi = ln >> 4;
  for (int c = wv; c < 18; c += 4){
    const int jt = c >> 1, mi = c & 1;
    bf16x8 v;
    #pragma unroll
    for (int idx8 = 0; idx8 < 8; ++idx8){
      const int ni = idx8 >> 2, r = idx8 & 3;
      int row = qt*32 + mi*16 + lhi*4 + r; if (row > 256) row = 256;
      int col = jt*32 + ni*16 + l16;       if (col > 263) col = 263;
      v[idx8] = (short)biasO[((long)bh*SS + row)*BSTR + col];
    }
    *(bf16x8*)(biasT + ((((long)bh*9 + qt)*9 + jt)*2 + mi)*512 + ln*8) = v;
  }
}

// ---------------- input projection + cls prepend ----------------
__global__ __launch_bounds__(256) void proj_kernel(
    const float* __restrict__ x_node, const float* __restrict__ Wp,
    const float* __restrict__ bp, const float* __restrict__ cls, float* __restrict__ hb)
{
  const int t = blockIdx.x;
  const int tid = threadIdx.x;
  const int b = t / SS, s2 = t - b*SS;
  float2 o;
  if (s2 == 0){
    o = *(const float2*)(cls + tid*2);
  } else {
    const float* xr = x_node + ((long)b*NN + (s2-1))*16;
    float xv[16];
    #pragma unroll
    for (int c2 = 0; c2 < 16; ++c2) xv[c2] = xr[c2];
    float oo[2];
    #pragma unroll
    for (int e = 0; e < 2; ++e){
      int d = tid*2 + e;
      float a = bp[d];
      const float* wr2 = Wp + (long)d*16;
      #pragma unroll
      for (int c2 = 0; c2 < 16; ++c2) a += xv[c2]*wr2[c2];
      oo[e] = a;
    }
    o.x = oo[0]; o.y = oo[1];
  }
  *(float2*)(hb + (long)t*DD + tid*2) = o;
}

// ---------------- LayerNorm f32 -> bf16, wave-per-token ----------------
__global__ __launch_bounds__(256) void ln_kernel(
    const float* __restrict__ hb, const float* __restrict__ w,
    const float* __restrict__ bbv, unsigned short* __restrict__ xb)
{
  const int tok = blockIdx.x*4 + (threadIdx.x >> 6);
  const int lane = threadIdx.x & 63;
  const float4* p = (const float4*)(hb + (long)tok*DD + lane*8);
  const float4 a = p[0], bq = p[1];
  float s  = a.x + a.y + a.z + a.w + bq.x + bq.y + bq.z + bq.w;
  float ss = a.x*a.x + a.y*a.y + a.z*a.z + a.w*a.w
           + bq.x*bq.x + bq.y*bq.y + bq.z*bq.z + bq.w*bq.w;
  #pragma unroll
  for (int m = 1; m < 64; m <<= 1){ s += __shfl_xor(s, m); ss += __shfl_xor(ss, m); }
  const float mu = s * (1.f/DD);
  const float var = ss * (1.f/DD) - mu*mu;
  const float rs = rsqrtf(var + 1e-5f);
  const float4* wp = (const float4*)(w + lane*8);
  const float4* bp2 = (const float4*)(bbv + lane*8);
  const float4 w0 = wp[0], w1 = wp[1];
  const float4 b0 = bp2[0], b1 = bp2[1];
  bf16x8 o;
  o[0] = (short)f2b((a.x - mu)*rs*w0.x + b0.x);
  o[1] = (short)f2b((a.y - mu)*rs*w0.y + b0.y);
  o[2] = (short)f2b((a.z - mu)*rs*w0.z + b0.z);
  o[3] = (short)f2b((a.w - mu)*rs*w0.w + b0.w);
  o[4] = (short)f2b((bq.x - mu)*rs*w1.x + b1.x);
  o[5] = (short)f2b((bq.y - mu)*rs*w1.y + b1.y);
  o[6] = (short)f2b((bq.z - mu)*rs*w1.z + b1.z);
  o[7] = (short)f2b((bq.w - mu)*rs*w1.w + b1.w);
  *(bf16x8*)(xb + (long)tok*DD + lane*8) = o;
}

// ---------------- MFMA GEMM: C = A[M,K] @ W[N,K]^T (+bias) ----------------
// R8/R10-proven structure: single LDS buffer, implicit-drain K-loop.
// MI/NI = m/n-subtiles per wave: BM = MI*32, BN = NI*32.
// WPE = waves/EU bound. Pool 512 VGPR/SIMD: MI=4,NI=4 ~124 regs -> WPE=4 max;
// MI=4,NI=2 ~76 regs -> WPE=6 fits.
// EPI: 0 = bf16 store, 1 = bf16 relu store,
//      2 = f32 C += via LDS-staged VECTORIZED epilogue.
template<int EPI, int MI, int NI, int WPE>
__global__ __launch_bounds__(256, WPE) void gemm_kernel(
    const unsigned short* __restrict__ A, const unsigned short* __restrict__ Bw,
    const float* __restrict__ bias, void* __restrict__ Cout,
    int M, int N, int K, int ldc, int nblocks)
{
  __shared__ __align__(16) char smem[MI*4096 + NI*4096];
  unsigned short* As = (unsigned short*)smem;
  unsigned short* Bs = (unsigned short*)(smem + MI*4096);
  const int tid = threadIdx.x;
  const int lane = tid & 63;
  const int wave = tid >> 6;
  const int wr = wave >> 1, wc = wave & 1;
  const int l16 = lane & 15, lhi = lane >> 4;

  const int nwg = gridDim.x;
  const int q8 = nwg >> 3, r8 = nwg & 7;
  const int xcd = blockIdx.x & 7, idx = blockIdx.x >> 3;
  const int lin = (xcd < r8 ? xcd*(q8+1) : r8*(q8+1) + (xcd-r8)*q8) + idx;
  const int mb = lin / nblocks;
  const int nb = lin - mb*nblocks;
  const long m0 = (long)mb * (MI*32);
  const long n0 = (long)nb * (NI*32);

  f32x4 acc[MI][NI];
  const f32x4 z4 = {0.f, 0.f, 0.f, 0.f};
  #pragma unroll
  for (int mi = 0; mi < MI; ++mi)
    #pragma unroll
    for (int ni = 0; ni < NI; ++ni) acc[mi][ni] = z4;

  const char* Ab = (const char*)A;
  const char* Bb = (const char*)Bw;
  const int nkt = K >> 6;
  for (int kt = 0; kt < nkt; ++kt){
    #pragma unroll
    for (int c = 0; c < MI; ++c){
      const int bo = c*4096 + tid*16;
      const int row = bo >> 7;
      const int kb = bo & 127;
      gl_lds16(Ab + ((m0+row)*(long)K)*2 + (long)kt*128 + kb, (char*)As + bo);
    }
    #pragma unroll
    for (int c = 0; c < NI; ++c){
      const int bo = c*4096 + tid*16;
      const int row = bo >> 7;
      const int kb = bo & 127;
      gl_lds16(Bb + ((n0+row)*(long)K)*2 + (long)kt*128 + kb, (char*)Bs + bo);
    }
    __syncthreads();
    #pragma unroll
    for (int kd = 0; kd < 2; ++kd){
      bf16x8 af[MI], bfr[NI];
      #pragma unroll
      for (int mi = 0; mi < MI; ++mi)
        af[mi] = *(const bf16x8*)((const char*)As + (wr*(MI*16) + mi*16 + l16)*128 + kd*64 + lhi*16);
      #pragma unroll
      for (int ni = 0; ni < NI; ++ni)
        bfr[ni] = *(const bf16x8*)((const char*)Bs + (wc*(NI*16) + ni*16 + l16)*128 + kd*64 + lhi*16);
      #pragma unroll
      for (int mi = 0; mi < MI; ++mi)
        #pragma unroll
        for (int ni = 0; ni < NI; ++ni)
          acc[mi][ni] = __builtin_amdgcn_mfma_f32_16x16x32_bf16(af[mi], bfr[ni], acc[mi][ni], 0, 0, 0);
    }
    __syncthreads();
  }

  if (EPI == 2){
    float* Cs = (float*)smem;          // reuses As/Bs (dead after K-loop)
    const int NC = NI*32;              // 64
    const int LDSC = NC + 4;           // 68
    float* Cg = (float*)Cout;
    #pragma unroll
    for (int half = 0; half < 2; ++half){
      if (wr == half){
        #pragma unroll
        for (int mi = 0; mi < MI; ++mi)
          #pragma unroll
          for (int ni = 0; ni < NI; ++ni){
            const int col = wc*(NI*16) + ni*16 + l16;
            #pragma unroll
            for (int r = 0; r < 4; ++r)
              Cs[(mi*16 + lhi*4 + r)*LDSC + col] = acc[mi][ni][r];
          }
      }
      __syncthreads();
      #pragma unroll
      for (int it = 0; it < MI; ++it){
        const int idx = tid + it*256;
        const int c4 = idx & 15;
        const int row = idx >> 4;
        const int gm = (int)m0 + half*(MI*16) + row;
        if (gm < M){
          const long go = (long)gm*ldc + n0 + c4*4;
          float4 cv = *(float4*)&Cg[go];
          const float* ls = &Cs[row*LDSC + c4*4];
          const float4 bv = *(const float4*)&bias[n0 + c4*4];
          cv.x += ls[0] + bv.x; cv.y += ls[1] + bv.y;
          cv.z += ls[2] + bv.z; cv.w += ls[3] + bv.w;
          *(float4*)&Cg[go] = cv;
        }
      }
      __syncthreads();
    }
  } else {
    #pragma unroll
    for (int mi = 0; mi < MI; ++mi){
      #pragma unroll
      for (int ni = 0; ni < NI; ++ni){
        const int col = (int)n0 + wc*(NI*16) + ni*16 + l16;
        const float bn = bias[col];
        const int rowb = (int)m0 + wr*(MI*16) + mi*16 + lhi*4;
        #pragma unroll
        for (int r = 0; r < 4; ++r){
          const int m = rowb + r;
          if (m < M){
            float v = acc[mi][ni][r] + bn;
            if (EPI == 1) v = fmaxf(v, 0.f);
            ((unsigned short*)Cout)[(long)m*ldc + col] = f2b(v);
          }
        }
      }
    }
  }
}

// ---------------- V transpose: qkv v-slice -> vt[bh*64+d][s] ----------------
__global__ __launch_bounds__(256) void vtrans_kernel(
    const unsigned short* __restrict__ qkv, unsigned short* __restrict__ vt)
{
  const int bh = blockIdx.x;
  const int c = blockIdx.y;       // 0..4, covers s in [c*64, c*64+64)
  const int b = bh >> 3, h = bh & 7;
  __shared__ unsigned short tile[64][72];
  const int tid = threadIdx.x;
  const int rr = tid >> 3, ch = tid & 7;
  #pragma unroll
  for (int it = 0; it < 2; ++it){
    const int sl = it*32 + rr;
    const long tok = (long)b*SS + c*64 + sl;   // <= 16510 < MPAD
    bf16x8 v = *(const bf16x8*)(qkv + tok*1536 + 1024 + h*64 + ch*8);
    *(bf16x8*)(&tile[sl][ch*8]) = v;
  }
  __syncthreads();
  #pragma unroll
  for (int it = 0; it < 2; ++it){
    const int d = it*32 + rr;
    const int s0 = c*64 + ch*8;
    bf16x8 o;
    #pragma unroll
    for (int e = 0; e < 8; ++e){
      const int sgl = s0 + e;
      o[e] = (sgl < SS) ? (short)tile[ch*8 + e][d] : (short)0;
    }
    *(bf16x8*)(vt + ((long)bh*HDD + d)*VSTR + s0) = o;
  }
}

// ---------------- flash attention: 3-wave blocks, grid (bh, qgroup) --------
// Was 9-wave blocks at 512 blocks = 2/CU (grid-limited, 9-wave barrier
// convoys). Now 1536 blocks x 3 waves: ~7 blocks/CU, independent small
// convoys. Each block stages its own K/V tiles (8 chunks split 3/3/2 over
// its waves; K/V slices are L2/L3-resident so the x3 duplication is cheap).
// Bias via fragment-layout biasT register prefetch (2 bf16x8 loads/jt).
__global__ __launch_bounds__(192) void flash_kernel(
    const unsigned short* __restrict__ qkv, const unsigned short* __restrict__ vt,
    const unsigned short* __restrict__ biasT, unsigned short* __restrict__ ob)
{
  const int bh = blockIdx.x;     // 0..511
  const int b = bh >> 3, h = bh & 7;
  const int wave = threadIdx.x >> 6;     // 0..2
  const int qt = blockIdx.y*3 + wave;    // 0..8
  const int lane = threadIdx.x & 63;
  const int l16 = lane & 15, lhi = lane >> 4;

  __shared__ unsigned short Ks[2][2048];   // [s32][d64] swizzled chunks
  __shared__ unsigned short Vs[2][2048];   // [d64][s32] swizzled chunks
  __shared__ unsigned short pt[3][1024];
  unsigned short* ptw = pt[wave];

  bf16x8 qf[2][2];
  #pragma unroll
  for (int mi = 0; mi < 2; ++mi)
    #pragma unroll
    for (int kd = 0; kd < 2; ++kd){
      const long tok = (long)b*SS + qt*32 + mi*16 + l16;
      qf[mi][kd] = *(const bf16x8*)(qkv + tok*1536 + h*64 + kd*32 + lhi*8);
    }

  // stage K/V tile jtn into buffer bb: 8 chunks (4 K quarters, 4 V quarters)
  // split over 3 waves (wave w takes chunks w, w+3, w+6 -> 3/3/2 calls).
  auto stage = [&](int jtn, int bb){
    for (int c = wave; c < 8; c += 3){
      if (c < 4){
        const int rK = lane >> 3, cK = lane & 7;
        gl_lds16((const char*)qkv + (((long)b*SS + jtn*32 + c*8 + rK)*1536 + 512 + h*64)*2 + ((cK ^ rK)*16),
                 (char*)&Ks[bb][0] + c*1024 + lane*16);
      } else {
        const int cv2 = c - 4;
        const int rV = lane >> 2, cV = lane & 3;
        const int d = cv2*16 + rV;
        gl_lds16((const char*)vt + (((long)bh*64 + d)*VSTR + (long)jtn*32)*2 + ((cV ^ (rV & 3))*16),
                 (char*)&Vs[bb][0] + cv2*1024 + lane*16);
      }
    }
  };

  // per-wave bias fragment register double-buffer (A = even jt, B = odd jt)
  const long tqb = ((long)bh*9 + qt)*9;
  bf16x8 btA0, btA1, btB0, btB1;
  btA0 = *(const bf16x8*)(biasT + (tqb + 0)*1024 + lane*8);
  btA1 = *(const bf16x8*)(biasT + (tqb + 0)*1024 + 512 + lane*8);
  btB0 = btA0; btB1 = btA1;

  f32x4 oacc[2][4];
  const f32x4 z4 = {0.f, 0.f, 0.f, 0.f};
  #pragma unroll
  for (int mi = 0; mi < 2; ++mi)
    #pragma unroll
    for (int ni = 0; ni < 4; ++ni) oacc[mi][ni] = z4;
  float mrow[2][4], lrow[2][4];
  #pragma unroll
  for (int mi = 0; mi < 2; ++mi)
    #pragma unroll
    for (int r = 0; r < 4; ++r){ mrow[mi][r] = -1e30f; lrow[mi][r] = 0.f; }

  stage(0, 0);
  __builtin_amdgcn_sched_barrier(0);

  for (int jt = 0; jt < 9; ++jt){
    const int cur = jt & 1;
    if (jt < 8){
      stage(jt+1, cur ^ 1);
      // prefetch next bias fragments into the other register set
      const long tbn = (tqb + (jt+1))*1024;
      if (cur){
        btA0 = *(const bf16x8*)(biasT + tbn + lane*8);
        btA1 = *(const bf16x8*)(biasT + tbn + 512 + lane*8);
      } else {
        btB0 = *(const bf16x8*)(biasT + tbn + lane*8);
        btB1 = *(const bf16x8*)(biasT + tbn + 512 + lane*8);
      }
      __builtin_amdgcn_sched_barrier(0);
      // newest in flight for THIS wave: own stage chunks + 2 bias loads.
      if (wave < 2) asm volatile("s_waitcnt vmcnt(5)" ::: "memory");
      else          asm volatile("s_waitcnt vmcnt(4)" ::: "memory");
    } else {
      asm volatile("s_waitcnt vmcnt(0)" ::: "memory");
    }
    __builtin_amdgcn_sched_barrier(0);
    __builtin_amdgcn_s_barrier();
    __builtin_amdgcn_sched_barrier(0);

    const bf16x8 bt0 = cur ? btB0 : btA0;
    const bf16x8 bt1 = cur ? btB1 : btA1;

    bf16x8 kf[2][2];
    #pragma unroll
    for (int ni = 0; ni < 2; ++ni)
      #pragma unroll
      for (int kd = 0; kd < 2; ++kd){
        const int row = ni*16 + l16;
        const int sw = (kd*4 + lhi) ^ (row & 7);
        kf[ni][kd] = *(const bf16x8*)((const char*)&Ks[cur][0] + row*128 + sw*16);
      }
    f32x4 sacc[2][2];
    #pragma unroll
    for (int mi = 0; mi < 2; ++mi)
      #pragma unroll
      for (int ni = 0; ni < 2; ++ni) sacc[mi][ni] = z4;
    __builtin_amdgcn_s_setprio(1);
    #pragma unroll
    for (int kd = 0; kd < 2; ++kd)
      #pragma unroll
      for (int mi = 0; mi < 2; ++mi)
        #pragma unroll
        for (int ni = 0; ni < 2; ++ni)
          sacc[mi][ni] = __builtin_amdgcn_mfma_f32_16x16x32_bf16(qf[mi][kd], kf[ni][kd], sacc[mi][ni], 0, 0, 0);
    __builtin_amdgcn_s_setprio(0);

    float sv[2][2][4];
    #pragma unroll
    for (int mi = 0; mi < 2; ++mi)
      #pragma unroll
      for (int ni = 0; ni < 2; ++ni)
        #pragma unroll
        for (int r = 0; r < 4; ++r){
          const int col = jt*32 + ni*16 + l16;
          float x = sacc[mi][ni][r] * 0.125f;
          x += b2f((unsigned short)((mi ? bt1 : bt0)[ni*4 + r]));
          if (col >= SS) x = -1e30f;
          sv[mi][ni][r] = x;
        }
    #pragma unroll
    for (int mi = 0; mi < 2; ++mi)
      #pragma unroll
      for (int r = 0; r < 4; ++r){
        float pm = fmaxf(sv[mi][0][r], sv[mi][1][r]);
        #pragma unroll
        for (int sh = 1; sh < 16; sh <<= 1) pm = fmaxf(pm, __shfl_xor(pm, sh));
        const float mold = mrow[mi][r];
        const float mnew = fmaxf(mold, pm);
        const float corr = __expf(mold - mnew);
        mrow[mi][r] = mnew;
        float psum = 0.f;
        #pragma unroll
        for (int ni = 0; ni < 2; ++ni){
          const float p = __expf(sv[mi][ni][r] - mnew);
          sv[mi][ni][r] = p;
          psum += p;
        }
        #pragma unroll
        for (int sh = 1; sh < 16; sh <<= 1) psum += __shfl_xor(psum, sh);
        lrow[mi][r] = lrow[mi][r]*corr + psum;
        #pragma unroll
        for (int ni = 0; ni < 4; ++ni) oacc[mi][ni][r] = oacc[mi][ni][r]*corr;
      }
    #pragma unroll
    for (int mi = 0; mi < 2; ++mi)
      #pragma unroll
      for (int ni = 0; ni < 2; ++ni)
        #pragma unroll
        for (int r = 0; r < 4; ++r)
          ptw[(mi*16 + lhi*4 + r)*32 + ni*16 + l16] = f2b(sv[mi][ni][r]);
    bf16x8 pf[2];
    #pragma unroll
    for (int mi = 0; mi < 2; ++mi)
      pf[mi] = *(const bf16x8*)(ptw + (mi*16 + l16)*32 + lhi*8);
    bf16x8 vf[4];
    #pragma unroll
    for (int ni = 0; ni < 4; ++ni){
      const int d = ni*16 + l16;
      const int sw = lhi ^ (d & 3);
      vf[ni] = *(const bf16x8*)((const char*)&Vs[cur][0] + d*64 + sw*16);
    }
    __builtin_amdgcn_s_setprio(1);
    #pragma unroll
    for (int mi = 0; mi < 2; ++mi)
      #pragma unroll
      for (int ni = 0; ni < 4; ++ni)
        oacc[mi][ni] = __builtin_amdgcn_mfma_f32_16x16x32_bf16(pf[mi], vf[ni], oacc[mi][ni], 0, 0, 0);
    __builtin_amdgcn_s_setprio(0);

    __builtin_amdgcn_sched_barrier(0);
    __builtin_amdgcn_s_barrier();
    __builtin_amdgcn_sched_barrier(0);
  }

  #pragma unroll
  for (int mi = 0; mi < 2; ++mi)
    #pragma unroll
    for (int r = 0; r < 4; ++r){
      const int row = qt*32 + mi*16 + lhi*4 + r;
      if (row < SS){
        const float inv = 1.0f / lrow[mi][r];
        const long tok = (long)b*SS + row;
        #pragma unroll
        for (int ni = 0; ni < 4; ++ni)
          ob[tok*DD + h*HDD + ni*16 + l16] = f2b(oacc[mi][ni][r] * inv);
      }
    }
}

// ---------------- classifier head ----------------
__global__ __launch_bounds__(256) void cls_kernel(
    const float* __restrict__ hb, const float* __restrict__ lw, const float* __restrict__ lb,
    const float* __restrict__ w1, const float* __restrict__ b1,
    const float* __restrict__ w2, const float* __restrict__ b2, float* __restrict__ out)
{
  const int b = blockIdx.x;
  const int tid = threadIdx.x;
  const float* row = hb + (long)b*SS*DD;
  const float2 v = *(const float2*)(row + tid*2);
  float s = v.x + v.y, ss = v.x*v.x + v.y*v.y;
  #pragma unroll
  for (int m = 1; m < 64; m <<= 1){ s += __shfl_xor(s, m); ss += __shfl_xor(ss, m); }
  __shared__ float red[8];
  const int wv = tid >> 6;
  if ((tid & 63) == 0){ red[wv] = s; red[4+wv] = ss; }
  __syncthreads();
  s  = red[0]+red[1]+red[2]+red[3];
  ss = red[4]+red[5]+red[6]+red[7];
  const float mu = s * (1.f/DD);
  const float var = ss * (1.f/DD) - mu*mu;
  const float rs = rsqrtf(var + 1e-5f);
  __shared__ __align__(16) float xs[DD];
  xs[tid*2]   = (v.x - mu)*rs*lw[tid*2]   + lb[tid*2];
  xs[tid*2+1] = (v.y - mu)*rs*lw[tid*2+1] + lb[tid*2+1];
  __syncthreads();
  float a = b1[tid];
  const float4* w1v = (const float4*)(w1 + (long)tid*DD);
  const float4* xsv = (const float4*)xs;
  for (int d4 = 0; d4 < DD/4; ++d4){
    const float4 wv4 = w1v[d4], xv4 = xsv[d4];
    a += wv4.x*xv4.x + wv4.y*xv4.y + wv4.z*xv4.z + wv4.w*xv4.w;
  }
  const float g = 0.5f*a*(1.f + erff(a*0.70710678118f));
  float p0 = g * w2[tid];
  float p1 = g * w2[256 + tid];
  #pragma unroll
  for (int m = 1; m < 64; m <<= 1){ p0 += __shfl_xor(p0, m); p1 += __shfl_xor(p1, m); }
  __shared__ float r2[8];
  if ((tid & 63) == 0){ r2[wv] = p0; r2[4+wv] = p1; }
  __syncthreads();
  if (tid == 0) out[b*2]   = r2[0]+r2[1]+r2[2]+r2[3] + b2[0];
  if (tid == 1) out[b*2+1] = r2[4]+r2[5]+r2[6]+r2[7] + b2[1];
}

extern "C" void kernel_launch(void* const* d_in, const int* in_sizes, int n_in,
                              void* d_out, int out_size, void* d_ws, size_t ws_size,
                              hipStream_t stream) {
  const float* x_node    = (const float*)d_in[0];
  const float* x_full    = (const float*)d_in[1];
  const float* Wp        = (const float*)d_in[2];
  const float* bp        = (const float*)d_in[3];
  const float* cls       = (const float*)d_in[4];
  const float* e_w1      = (const float*)d_in[5];
  const float* e_b1      = (const float*)d_in[6];
  const float* e_w2      = (const float*)d_in[7];
  const float* e_b2      = (const float*)d_in[8];
  const float* edge_scale= (const float*)d_in[9];
  const float* qkv_w     = (const float*)d_in[10];
  const float* qkv_b     = (const float*)d_in[11];
  const float* out_w     = (const float*)d_in[12];
  const float* out_b     = (const float*)d_in[13];
  const float* ln1_w     = (const float*)d_in[14];
  const float* ln1_b     = (const float*)d_in[15];
  const float* ln2_w     = (const float*)d_in[16];
  const float* ln2_b     = (const float*)d_in[17];
  const float* ff1_w     = (const float*)d_in[18];
  const float* ff1_b     = (const float*)d_in[19];
  const float* ff2_w     = (const float*)d_in[20];
  const float* ff2_b     = (const float*)d_in[21];
  const float* cl_ln_w   = (const float*)d_in[22];
  const float* cl_ln_b   = (const float*)d_in[23];
  const float* cl_w1     = (const float*)d_in[24];
  const float* cl_b1     = (const float*)d_in[25];
  const float* cl_w2     = (const float*)d_in[26];
  const float* cl_b2     = (const float*)d_in[27];
  float* out = (float*)d_out;

  char* w = (char*)d_ws;
  size_t off = 0;
  auto take = [&](size_t bytes)->char*{
    char* p = w + off;
    off += (bytes + 255) & ~(size_t)255;
    return p;
  };
  // Workspace: bias16 aliases qkvb/vtb (dead after brepack); flash output
  // reuses xb. Total ~258 MB <= proven 260.7 MB (R12).
  unsigned short* wq8   = (unsigned short*)take((size_t)LL*1536*512*2);
  unsigned short* wo8   = (unsigned short*)take((size_t)LL*512*512*2);
  unsigned short* wf1   = (unsigned short*)take((size_t)LL*2048*512*2);
  unsigned short* wf2   = (unsigned short*)take((size_t)LL*512*2048*2);
  unsigned short* biasT = (unsigned short*)take((size_t)512*81*1024*2);   // fragment-layout bias
  float*          cent  = (float*)take((size_t)BB*NN*HH*4);
  float*          hbuf  = (float*)take((size_t)MPAD*DD*4);
  unsigned short* xb    = (unsigned short*)take((size_t)MPAD*DD*2);
  unsigned short* qkvb  = (unsigned short*)take((size_t)MPAD*1536*2);
  unsigned short* vtb   = (unsigned short*)take((size_t)BB*HH*HDD*VSTR*2);
  unsigned short* ffb   = qkvb;     // union: FF intermediate reuses dead qkv region
  unsigned short* bias16= qkvb;     // union: original-layout bias lives in qkvb+vtb pre-loop
  unsigned short* obuf  = xb;       // union: flash output reuses xb

  // weights -> bf16
  cvt_kernel<<<4096, 256, 0, stream>>>(qkv_w, wq8, LL*1536*512/2);
  cvt_kernel<<<4096, 256, 0, stream>>>(out_w, wo8, LL*512*512/2);
  cvt_kernel<<<4096, 256, 0, stream>>>(ff1_w, wf1, LL*2048*512/2);
  cvt_kernel<<<4096, 256, 0, stream>>>(ff2_w, wf2, LL*512*2048/2);

  edge_kernel<<<dim3(BB*NN), 256, 0, stream>>>(x_full, e_w1, e_b1, e_w2, e_b2, bias16, cent);
  edge_border_kernel<<<dim3(BB*HH), 256, 0, stream>>>(cent, edge_scale, bias16);
  brepack_kernel<<<dim3(512, 9), 256, 0, stream>>>(bias16, biasT);
  proj_kernel<<<dim3(MTOK), 256, 0, stream>>>(x_node, Wp, bp, cls, hbuf);

  for (int l = 0; l < LL; ++l){
    ln_kernel<<<dim3(MTOK/4), 256, 0, stream>>>(hbuf, ln1_w + l*DD, ln1_b + l*DD, xb);
    gemm_kernel<0,4,4,4><<<dim3(129*12), 256, 0, stream>>>(xb, wq8 + (size_t)l*1536*512,
        qkv_b + (size_t)l*1536, qkvb, MTOK, 1536, 512, 1536, 12);
    vtrans_kernel<<<dim3(512, 5), 256, 0, stream>>>(qkvb, vtb);
    flash_kernel<<<dim3(512, 3), 192, 0, stream>>>(qkvb, vtb, biasT, obuf);
    gemm_kernel<2,4,2,6><<<dim3(129*8), 256, 0, stream>>>(obuf, wo8 + (size_t)l*512*512,
        out_b + (size_t)l*DD, hbuf, MTOK, 512, 512, 512, 8);
    ln_kernel<<<dim3(MTOK/4), 256, 0, stream>>>(hbuf, ln2_w + l*DD, ln2_b + l*DD, xb);
    gemm_kernel<1,4,4,4><<<dim3(129*16), 256, 0, stream>>>(xb, wf1 + (size_t)l*2048*512,
        ff1_b + (size_t)l*2048, ffb, MTOK, 2048, 512, 2048, 16);
    gemm_kernel<2,4,2,6><<<dim3(129*8), 256, 0, stream>>>(ffb, wf2 + (size_t)l*512*2048,
        ff2_b + (size_t)l*DD, hbuf, MTOK, 512, 2048, 512, 8);
  }
  cls_kernel<<<dim3(BB), 256, 0, stream>>>(hbuf, cl_ln_w, cl_ln_b, cl_w1, cl_b1, cl_w2, cl_b2, out);
}

// Round 18
// 2527.810 us; speedup vs baseline: 1.0563x; 1.0563x over previous
//
#include <hip/hip_runtime.h>
#include <hip/hip_bf16.h>
#include <stdint.h>

#define PI_F     3.14159265358979323846f
#define TWO_PI_F 6.28318530717958647692f
#define INV2PI_F 0.15915494309189535f

typedef __attribute__((ext_vector_type(8))) short bf16x8;
typedef __attribute__((ext_vector_type(4))) float f32x4;

#define BB 64
#define NN 256
#define SS 257
#define DD 512
#define HH 8
#define HDD 64
#define LL 8
#define MTOK 16448
#define MPAD 16512
#define BSTR 264
#define VSTR 320

__device__ __forceinline__ float b2f(unsigned short u){
  union { float f; uint32_t i; } c; c.i = ((uint32_t)u) << 16; return c.f;
}
__device__ __forceinline__ unsigned short f2b(float f){
  union { float f; uint32_t i; } c; c.f = f;
  uint32_t r = c.i + 0x7FFFu + ((c.i >> 16) & 1u);
  return (unsigned short)(r >> 16);
}
// fast gelu (tanh form, exp-based; rcpf for the divide). |err| vs erf-gelu
// ~5e-4, negligible after the *e_w2 (~0.01) contraction and bf16 store.
__device__ __forceinline__ float gelu_fast(float z){
  const float z2 = z*z;
  const float u2 = z * (1.5957691216f + 0.071354816f*z2);
  const float e = __expf(u2);
  const float r = __builtin_amdgcn_rcpf(1.f + e);
  const float th = 1.f - 2.f*r;
  return 0.5f*z*(1.f + th);
}

typedef __attribute__((address_space(1))) unsigned char ga_t;
typedef __attribute__((address_space(3))) unsigned char ls_t;
__device__ __forceinline__ void gl_lds16(const void* g, void* l){
  __builtin_amdgcn_global_load_lds((ga_t*)g, (ls_t*)l, 16, 0, 0);
}

// ---------------- weight f32 -> bf16 ----------------
__global__ __launch_bounds__(256) void cvt_kernel(const float* __restrict__ src,
                                                  unsigned short* __restrict__ dst, int n2){
  int i = blockIdx.x*256 + threadIdx.x;
  int stride = gridDim.x*256;
  for (; i < n2; i += stride){
    float2 v = ((const float2*)src)[i];
    ((uint32_t*)dst)[i] = (uint32_t)f2b(v.x) | ((uint32_t)f2b(v.y) << 16);
  }
}

// ---------------- edge MLP: interior bias + row means ----------------
__global__ __launch_bounds__(256) void edge_kernel(
    const float* __restrict__ x_full, const float* __restrict__ e_w1, const float* __restrict__ e_b1,
    const float* __restrict__ e_w2, const float* __restrict__ e_b2,
    unsigned short* __restrict__ bias, float* __restrict__ central)
{
  const int bi = blockIdx.x;
  const int b = bi >> 8, i = bi & 255;
  const int j = threadIdx.x;
  const float yi = x_full[((long)b*NN + i)*16 + 14];
  const float fi = x_full[((long)b*NN + i)*16 + 15];
  const float yj = x_full[((long)b*NN + j)*16 + 14];
  const float fj = x_full[((long)b*NN + j)*16 + 15];
  const float dy = fabsf(yi - yj);
  const float xw = fi - fj + PI_F;
  const float tw = xw * INV2PI_F;
  const float md = (tw - floorf(tw)) * TWO_PI_F;
  const float dphi = fabsf(md - PI_F);
  const float dr = sqrtf(dy*dy + dphi*dphi + 1e-8f);
  float raw[8];
  #pragma unroll
  for (int hh = 0; hh < 8; ++hh) raw[hh] = e_b2[hh];
  #pragma unroll
  for (int k = 0; k < 16; ++k){
    float z = e_w1[k*3]*dy + e_w1[k*3+1]*dphi + e_w1[k*3+2]*dr + e_b1[k];
    float g = gelu_fast(z);
    #pragma unroll
    for (int hh = 0; hh < 8; ++hh) raw[hh] += g * e_w2[hh*16 + k];
  }
  #pragma unroll
  for (int hh = 0; hh < 8; ++hh)
    bias[(((long)b*HH + hh)*SS + 1 + i)*BSTR + 1 + j] = f2b(raw[hh]);
  #pragma unroll
  for (int m = 1; m < 64; m <<= 1)
    #pragma unroll
    for (int hh = 0; hh < 8; ++hh) raw[hh] += __shfl_xor(raw[hh], m);
  __shared__ float cw[4][8];
  const int wv = j >> 6;
  if ((j & 63) == 0)
    for (int hh = 0; hh < 8; ++hh) cw[wv][hh] = raw[hh];
  __syncthreads();
  if (j < 8){
    float t = cw[0][j] + cw[1][j] + cw[2][j] + cw[3][j];
    central[((long)b*NN + i)*HH + j] = t * (1.f/NN);
  }
}

__global__ __launch_bounds__(256) void edge_border_kernel(
    const float* __restrict__ central, const float* __restrict__ edge_scale,
    unsigned short* __restrict__ bias)
{
  const int bh = blockIdx.x;
  const int b = bh >> 3, h = bh & 7;
  const int j = threadIdx.x;
  const float es = edge_scale[0];
  const float cv = central[((long)b*NN + j)*HH + h] * es;
  const long base = (long)bh*SS*BSTR;
  const unsigned short u = f2b(cv);
  bias[base + 1 + j] = u;                 // row 0 (CLS query)
  bias[base + (long)(1+j)*BSTR] = u;      // col 0 (CLS key)
  if (j == 0) bias[base] = 0;
}

// ---------------- input projection + cls prepend ----------------
__global__ __launch_bounds__(256) void proj_kernel(
    const float* __restrict__ x_node, const float* __restrict__ Wp,
    const float* __restrict__ bp, const float* __restrict__ cls, float* __restrict__ hb)
{
  const int t = blockIdx.x;
  const int tid = threadIdx.x;
  const int b = t / SS, s2 = t - b*SS;
  float2 o;
  if (s2 == 0){
    o = *(const float2*)(cls + tid*2);
  } else {
    const float* xr = x_node + ((long)b*NN + (s2-1))*16;
    float xv[16];
    #pragma unroll
    for (int c2 = 0; c2 < 16; ++c2) xv[c2] = xr[c2];
    float oo[2];
    #pragma unroll
    for (int e = 0; e < 2; ++e){
      int d = tid*2 + e;
      float a = bp[d];
      const float* wr2 = Wp + (long)d*16;
      #pragma unroll
      for (int c2 = 0; c2 < 16; ++c2) a += xv[c2]*wr2[c2];
      oo[e] = a;
    }
    o.x = oo[0]; o.y = oo[1];
  }
  *(float2*)(hb + (long)t*DD + tid*2) = o;
}

// ---------------- LayerNorm f32 -> bf16, wave-per-token ----------------
__global__ __launch_bounds__(256) void ln_kernel(
    const float* __restrict__ hb, const float* __restrict__ w,
    const float* __restrict__ bbv, unsigned short* __restrict__ xb)
{
  const int tok = blockIdx.x*4 + (threadIdx.x >> 6);
  const int lane = threadIdx.x & 63;
  const float4* p = (const float4*)(hb + (long)tok*DD + lane*8);
  const float4 a = p[0], bq = p[1];
  float s  = a.x + a.y + a.z + a.w + bq.x + bq.y + bq.z + bq.w;
  float ss = a.x*a.x + a.y*a.y + a.z*a.z + a.w*a.w
           + bq.x*bq.x + bq.y*bq.y + bq.z*bq.z + bq.w*bq.w;
  #pragma unroll
  for (int m = 1; m < 64; m <<= 1){ s += __shfl_xor(s, m); ss += __shfl_xor(ss, m); }
  const float mu = s * (1.f/DD);
  const float var = ss * (1.f/DD) - mu*mu;
  const float rs = rsqrtf(var + 1e-5f);
  const float4* wp = (const float4*)(w + lane*8);
  const float4* bp2 = (const float4*)(bbv + lane*8);
  const float4 w0 = wp[0], w1 = wp[1];
  const float4 b0 = bp2[0], b1 = bp2[1];
  bf16x8 o;
  o[0] = (short)f2b((a.x - mu)*rs*w0.x + b0.x);
  o[1] = (short)f2b((a.y - mu)*rs*w0.y + b0.y);
  o[2] = (short)f2b((a.z - mu)*rs*w0.z + b0.z);
  o[3] = (short)f2b((a.w - mu)*rs*w0.w + b0.w);
  o[4] = (short)f2b((bq.x - mu)*rs*w1.x + b1.x);
  o[5] = (short)f2b((bq.y - mu)*rs*w1.y + b1.y);
  o[6] = (short)f2b((bq.z - mu)*rs*w1.z + b1.z);
  o[7] = (short)f2b((bq.w - mu)*rs*w1.w + b1.w);
  *(bf16x8*)(xb + (long)tok*DD + lane*8) = o;
}

// ---------------- MFMA GEMM: C = A[M,K] @ W[N,K]^T (+bias) ----------------
// R8/R10-proven structure: single LDS buffer, implicit-drain K-loop.
// MI/NI = m/n-subtiles per wave: BM = MI*32, BN = NI*32.
// WPE = waves/EU bound. Pool 512 VGPR/SIMD: MI=4,NI=4 ~124 regs -> WPE=4 max;
// MI=4,NI=2 ~76 regs -> WPE=6 fits.
// EPI: 0 = bf16 store, 1 = bf16 relu store,
//      2 = f32 C += via LDS-staged VECTORIZED epilogue (the old per-element
//          scalar RMW ran at ~1.25 TB/s and was the shared fixed cost).
template<int EPI, int MI, int NI, int WPE>
__global__ __launch_bounds__(256, WPE) void gemm_kernel(
    const unsigned short* __restrict__ A, const unsigned short* __restrict__ Bw,
    const float* __restrict__ bias, void* __restrict__ Cout,
    int M, int N, int K, int ldc, int nblocks)
{
  __shared__ __align__(16) char smem[MI*4096 + NI*4096];
  unsigned short* As = (unsigned short*)smem;
  unsigned short* Bs = (unsigned short*)(smem + MI*4096);
  const int tid = threadIdx.x;
  const int lane = tid & 63;
  const int wave = tid >> 6;
  const int wr = wave >> 1, wc = wave & 1;
  const int l16 = lane & 15, lhi = lane >> 4;

  const int nwg = gridDim.x;
  const int q8 = nwg >> 3, r8 = nwg & 7;
  const int xcd = blockIdx.x & 7, idx = blockIdx.x >> 3;
  const int lin = (xcd < r8 ? xcd*(q8+1) : r8*(q8+1) + (xcd-r8)*q8) + idx;
  const int mb = lin / nblocks;
  const int nb = lin - mb*nblocks;
  const long m0 = (long)mb * (MI*32);
  const long n0 = (long)nb * (NI*32);

  f32x4 acc[MI][NI];
  const f32x4 z4 = {0.f, 0.f, 0.f, 0.f};
  #pragma unroll
  for (int mi = 0; mi < MI; ++mi)
    #pragma unroll
    for (int ni = 0; ni < NI; ++ni) acc[mi][ni] = z4;

  const char* Ab = (const char*)A;
  const char* Bb = (const char*)Bw;
  const int nkt = K >> 6;
  for (int kt = 0; kt < nkt; ++kt){
    #pragma unroll
    for (int c = 0; c < MI; ++c){
      const int bo = c*4096 + tid*16;
      const int row = bo >> 7;
      const int kb = bo & 127;
      gl_lds16(Ab + ((m0+row)*(long)K)*2 + (long)kt*128 + kb, (char*)As + bo);
    }
    #pragma unroll
    for (int c = 0; c < NI; ++c){
      const int bo = c*4096 + tid*16;
      const int row = bo >> 7;
      const int kb = bo & 127;
      gl_lds16(Bb + ((n0+row)*(long)K)*2 + (long)kt*128 + kb, (char*)Bs + bo);
    }
    __syncthreads();
    #pragma unroll
    for (int kd = 0; kd < 2; ++kd){
      bf16x8 af[MI], bfr[NI];
      #pragma unroll
      for (int mi = 0; mi < MI; ++mi)
        af[mi] = *(const bf16x8*)((const char*)As + (wr*(MI*16) + mi*16 + l16)*128 + kd*64 + lhi*16);
      #pragma unroll
      for (int ni = 0; ni < NI; ++ni)
        bfr[ni] = *(const bf16x8*)((const char*)Bs + (wc*(NI*16) + ni*16 + l16)*128 + kd*64 + lhi*16);
      #pragma unroll
      for (int mi = 0; mi < MI; ++mi)
        #pragma unroll
        for (int ni = 0; ni < NI; ++ni)
          acc[mi][ni] = __builtin_amdgcn_mfma_f32_16x16x32_bf16(af[mi], bfr[ni], acc[mi][ni], 0, 0, 0);
    }
    __syncthreads();
  }

  if (EPI == 2){
    // LDS-staged vectorized C += epilogue (instantiated with MI=4, NI=2:
    // BM=128, BN=64). Two 64-row halves: waves wr==half dump acc to a
    // padded f32 LDS tile, then all threads do coalesced float4 RMW.
    float* Cs = (float*)smem;          // reuses As/Bs (dead after K-loop)
    const int NC = NI*32;              // 64
    const int LDSC = NC + 4;           // 68
    float* Cg = (float*)Cout;
    #pragma unroll
    for (int half = 0; half < 2; ++half){
      if (wr == half){
        #pragma unroll
        for (int mi = 0; mi < MI; ++mi)
          #pragma unroll
          for (int ni = 0; ni < NI; ++ni){
            const int col = wc*(NI*16) + ni*16 + l16;
            #pragma unroll
            for (int r = 0; r < 4; ++r)
              Cs[(mi*16 + lhi*4 + r)*LDSC + col] = acc[mi][ni][r];
          }
      }
      __syncthreads();
      #pragma unroll
      for (int it = 0; it < MI; ++it){
        const int idx = tid + it*256;
        const int c4 = idx & 15;
        const int row = idx >> 4;
        const int gm = (int)m0 + half*(MI*16) + row;
        if (gm < M){
          const long go = (long)gm*ldc + n0 + c4*4;
          float4 cv = *(float4*)&Cg[go];
          const float* ls = &Cs[row*LDSC + c4*4];
          const float4 bv = *(const float4*)&bias[n0 + c4*4];
          cv.x += ls[0] + bv.x; cv.y += ls[1] + bv.y;
          cv.z += ls[2] + bv.z; cv.w += ls[3] + bv.w;
          *(float4*)&Cg[go] = cv;
        }
      }
      __syncthreads();
    }
  } else {
    #pragma unroll
    for (int mi = 0; mi < MI; ++mi){
      #pragma unroll
      for (int ni = 0; ni < NI; ++ni){
        const int col = (int)n0 + wc*(NI*16) + ni*16 + l16;
        const float bn = bias[col];
        const int rowb = (int)m0 + wr*(MI*16) + mi*16 + lhi*4;
        #pragma unroll
        for (int r = 0; r < 4; ++r){
          const int m = rowb + r;
          if (m < M){
            float v = acc[mi][ni][r] + bn;
            if (EPI == 1) v = fmaxf(v, 0.f);
            ((unsigned short*)Cout)[(long)m*ldc + col] = f2b(v);
          }
        }
      }
    }
  }
}

// ---------------- V transpose: qkv v-slice -> vt[bh*64+d][s] ----------------
__global__ __launch_bounds__(256) void vtrans_kernel(
    const unsigned short* __restrict__ qkv, unsigned short* __restrict__ vt)
{
  const int bh = blockIdx.x;
  const int c = blockIdx.y;       // 0..4, covers s in [c*64, c*64+64)
  const int b = bh >> 3, h = bh & 7;
  __shared__ unsigned short tile[64][72];
  const int tid = threadIdx.x;
  const int rr = tid >> 3, ch = tid & 7;
  #pragma unroll
  for (int it = 0; it < 2; ++it){
    const int sl = it*32 + rr;
    const long tok = (long)b*SS + c*64 + sl;   // <= 16510 < MPAD
    bf16x8 v = *(const bf16x8*)(qkv + tok*1536 + 1024 + h*64 + ch*8);
    *(bf16x8*)(&tile[sl][ch*8]) = v;
  }
  __syncthreads();
  #pragma unroll
  for (int it = 0; it < 2; ++it){
    const int d = it*32 + rr;
    const int s0 = c*64 + ch*8;
    bf16x8 o;
    #pragma unroll
    for (int e = 0; e < 8; ++e){
      const int sgl = s0 + e;
      o[e] = (sgl < SS) ? (short)tile[ch*8 + e][d] : (short)0;
    }
    *(bf16x8*)(vt + ((long)bh*HDD + d)*VSTR + s0) = o;
  }
}

// ---------------- flash attention: 1 block per (b,h), 9 waves = 9 q-tiles ----------------
// K/V/bias double-buffered in LDS via async global_load_lds, counted vmcnt,
// raw s_barrier (no full drain). K/V pre-swizzled (XOR 16B-chunk) for
// conflict-free ds_read_b128.
__global__ __launch_bounds__(576) void flash_kernel(
    const unsigned short* __restrict__ qkv, const unsigned short* __restrict__ vt,
    const unsigned short* __restrict__ bias, unsigned short* __restrict__ ob)
{
  const int bh = blockIdx.x;     // 0..511
  const int b = bh >> 3, h = bh & 7;
  const int qt = threadIdx.x >> 6;   // wave id = q-tile 0..8
  const int lane = threadIdx.x & 63;
  const int l16 = lane & 15, lhi = lane >> 4;

  __shared__ unsigned short Ks[2][2048];
  __shared__ unsigned short Vs[2][2048];
  __shared__ unsigned short Bsh[9][2][1024];
  __shared__ unsigned short pt[9][1024];
  unsigned short* ptw = pt[qt];

  bf16x8 qf[2][2];
  #pragma unroll
  for (int mi = 0; mi < 2; ++mi)
    #pragma unroll
    for (int kd = 0; kd < 2; ++kd){
      const long tok = (long)b*SS + qt*32 + mi*16 + l16;
      qf[mi][kd] = *(const bf16x8*)(qkv + tok*1536 + h*64 + kd*32 + lhi*8);
    }

  auto stage = [&](int jtn, int bb){
    const int rB = lane >> 2, cB = lane & 3;
    const char* gb = (const char*)bias + (((long)bh*SS + qt*32)*BSTR + (long)jtn*32)*2;
    char* lb = (char*)&Bsh[qt][bb][0];
    gl_lds16(gb + (long)rB*BSTR*2        + cB*16, lb + lane*16);
    gl_lds16(gb + (long)(16+rB)*BSTR*2   + cB*16, lb + 1024 + lane*16);
    if (qt < 4){
      const int rK = lane >> 3, cK = lane & 7;
      gl_lds16((const char*)qkv + (((long)b*SS + jtn*32 + qt*8 + rK)*1536 + 512 + h*64)*2 + ((cK ^ rK)*16),
               (char*)&Ks[bb][0] + qt*1024 + lane*16);
    } else if (qt < 8){
      const int rV = lane >> 2, cV = lane & 3;
      const int d = (qt-4)*16 + rV;
      gl_lds16((const char*)vt + (((long)bh*64 + d)*VSTR + (long)jtn*32)*2 + ((cV ^ (rV & 3))*16),
               (char*)&Vs[bb][0] + (qt-4)*1024 + lane*16);
    }
  };

  f32x4 oacc[2][4];
  const f32x4 z4 = {0.f, 0.f, 0.f, 0.f};
  #pragma unroll
  for (int mi = 0; mi < 2; ++mi)
    #pragma unroll
    for (int ni = 0; ni < 4; ++ni) oacc[mi][ni] = z4;
  float mrow[2][4], lrow[2][4];
  #pragma unroll
  for (int mi = 0; mi < 2; ++mi)
    #pragma unroll
    for (int r = 0; r < 4; ++r){ mrow[mi][r] = -1e30f; lrow[mi][r] = 0.f; }

  stage(0, 0);
  __builtin_amdgcn_sched_barrier(0);

  for (int jt = 0; jt < 9; ++jt){
    const int cur = jt & 1;
    if (jt < 8){
      stage(jt+1, cur ^ 1);
      __builtin_amdgcn_sched_barrier(0);
      if (qt < 8) asm volatile("s_waitcnt vmcnt(3)" ::: "memory");
      else        asm volatile("s_waitcnt vmcnt(2)" ::: "memory");
    } else {
      asm volatile("s_waitcnt vmcnt(0)" ::: "memory");
    }
    __builtin_amdgcn_sched_barrier(0);
    __builtin_amdgcn_s_barrier();
    __builtin_amdgcn_sched_barrier(0);

    bf16x8 kf[2][2];
    #pragma unroll
    for (int ni = 0; ni < 2; ++ni)
      #pragma unroll
      for (int kd = 0; kd < 2; ++kd){
        const int row = ni*16 + l16;
        const int sw = (kd*4 + lhi) ^ (row & 7);
        kf[ni][kd] = *(const bf16x8*)((const char*)&Ks[cur][0] + row*128 + sw*16);
      }
    f32x4 sacc[2][2];
    #pragma unroll
    for (int mi = 0; mi < 2; ++mi)
      #pragma unroll
      for (int ni = 0; ni < 2; ++ni) sacc[mi][ni] = z4;
    __builtin_amdgcn_s_setprio(1);
    #pragma unroll
    for (int kd = 0; kd < 2; ++kd)
      #pragma unroll
      for (int mi = 0; mi < 2; ++mi)
        #pragma unroll
        for (int ni = 0; ni < 2; ++ni)
          sacc[mi][ni] = __builtin_amdgcn_mfma_f32_16x16x32_bf16(qf[mi][kd], kf[ni][kd], sacc[mi][ni], 0, 0, 0);
    __builtin_amdgcn_s_setprio(0);

    float sv[2][2][4];
    #pragma unroll
    for (int mi = 0; mi < 2; ++mi)
      #pragma unroll
      for (int ni = 0; ni < 2; ++ni)
        #pragma unroll
        for (int r = 0; r < 4; ++r){
          const int col = jt*32 + ni*16 + l16;
          float x = sacc[mi][ni][r] * 0.125f;
          x += b2f(Bsh[qt][cur][(mi*16 + lhi*4 + r)*32 + ni*16 + l16]);
          if (col >= SS) x = -1e30f;
          sv[mi][ni][r] = x;
        }
    #pragma unroll
    for (int mi = 0; mi < 2; ++mi)
      #pragma unroll
      for (int r = 0; r < 4; ++r){
        float pm = fmaxf(sv[mi][0][r], sv[mi][1][r]);
        #pragma unroll
        for (int sh = 1; sh < 16; sh <<= 1) pm = fmaxf(pm, __shfl_xor(pm, sh));
        const float mold = mrow[mi][r];
        const float mnew = fmaxf(mold, pm);
        const float corr = __expf(mold - mnew);
        mrow[mi][r] = mnew;
        float psum = 0.f;
        #pragma unroll
        for (int ni = 0; ni < 2; ++ni){
          const float p = __expf(sv[mi][ni][r] - mnew);
          sv[mi][ni][r] = p;
          psum += p;
        }
        #pragma unroll
        for (int sh = 1; sh < 16; sh <<= 1) psum += __shfl_xor(psum, sh);
        lrow[mi][r] = lrow[mi][r]*corr + psum;
        #pragma unroll
        for (int ni = 0; ni < 4; ++ni) oacc[mi][ni][r] = oacc[mi][ni][r]*corr;
      }
    #pragma unroll
    for (int mi = 0; mi < 2; ++mi)
      #pragma unroll
      for (int ni = 0; ni < 2; ++ni)
        #pragma unroll
        for (int r = 0; r < 4; ++r)
          ptw[(mi*16 + lhi*4 + r)*32 + ni*16 + l16] = f2b(sv[mi][ni][r]);
    bf16x8 pf[2];
    #pragma unroll
    for (int mi = 0; mi < 2; ++mi)
      pf[mi] = *(const bf16x8*)(ptw + (mi*16 + l16)*32 + lhi*8);
    bf16x8 vf[4];
    #pragma unroll
    for (int ni = 0; ni < 4; ++ni){
      const int d = ni*16 + l16;
      const int sw = lhi ^ (d & 3);
      vf[ni] = *(const bf16x8*)((const char*)&Vs[cur][0] + d*64 + sw*16);
    }
    __builtin_amdgcn_s_setprio(1);
    #pragma unroll
    for (int mi = 0; mi < 2; ++mi)
      #pragma unroll
      for (int ni = 0; ni < 4; ++ni)
        oacc[mi][ni] = __builtin_amdgcn_mfma_f32_16x16x32_bf16(pf[mi], vf[ni], oacc[mi][ni], 0, 0, 0);
    __builtin_amdgcn_s_setprio(0);

    __builtin_amdgcn_sched_barrier(0);
    __builtin_amdgcn_s_barrier();
    __builtin_amdgcn_sched_barrier(0);
  }

  #pragma unroll
  for (int mi = 0; mi < 2; ++mi)
    #pragma unroll
    for (int r = 0; r < 4; ++r){
      const int row = qt*32 + mi*16 + lhi*4 + r;
      if (row < SS){
        const float inv = 1.0f / lrow[mi][r];
        const long tok = (long)b*SS + row;
        #pragma unroll
        for (int ni = 0; ni < 4; ++ni)
          ob[tok*DD + h*HDD + ni*16 + l16] = f2b(oacc[mi][ni][r] * inv);
      }
    }
}

// ---------------- classifier head ----------------
__global__ __launch_bounds__(256) void cls_kernel(
    const float* __restrict__ hb, const float* __restrict__ lw, const float* __restrict__ lb,
    const float* __restrict__ w1, const float* __restrict__ b1,
    const float* __restrict__ w2, const float* __restrict__ b2, float* __restrict__ out)
{
  const int b = blockIdx.x;
  const int tid = threadIdx.x;
  const float* row = hb + (long)b*SS*DD;
  const float2 v = *(const float2*)(row + tid*2);
  float s = v.x + v.y, ss = v.x*v.x + v.y*v.y;
  #pragma unroll
  for (int m = 1; m < 64; m <<= 1){ s += __shfl_xor(s, m); ss += __shfl_xor(ss, m); }
  __shared__ float red[8];
  const int wv = tid >> 6;
  if ((tid & 63) == 0){ red[wv] = s; red[4+wv] = ss; }
  __syncthreads();
  s  = red[0]+red[1]+red[2]+red[3];
  ss = red[4]+red[5]+red[6]+red[7];
  const float mu = s * (1.f/DD);
  const float var = ss * (1.f/DD) - mu*mu;
  const float rs = rsqrtf(var + 1e-5f);
  __shared__ __align__(16) float xs[DD];
  xs[tid*2]   = (v.x - mu)*rs*lw[tid*2]   + lb[tid*2];
  xs[tid*2+1] = (v.y - mu)*rs*lw[tid*2+1] + lb[tid*2+1];
  __syncthreads();
  float a = b1[tid];
  const float4* w1v = (const float4*)(w1 + (long)tid*DD);
  const float4* xsv = (const float4*)xs;
  for (int d4 = 0; d4 < DD/4; ++d4){
    const float4 wv4 = w1v[d4], xv4 = xsv[d4];
    a += wv4.x*xv4.x + wv4.y*xv4.y + wv4.z*xv4.z + wv4.w*xv4.w;
  }
  const float g = 0.5f*a*(1.f + erff(a*0.70710678118f));
  float p0 = g * w2[tid];
  float p1 = g * w2[256 + tid];
  #pragma unroll
  for (int m = 1; m < 64; m <<= 1){ p0 += __shfl_xor(p0, m); p1 += __shfl_xor(p1, m); }
  __shared__ float r2[8];
  if ((tid & 63) == 0){ r2[wv] = p0; r2[4+wv] = p1; }
  __syncthreads();
  if (tid == 0) out[b*2]   = r2[0]+r2[1]+r2[2]+r2[3] + b2[0];
  if (tid == 1) out[b*2+1] = r2[4]+r2[5]+r2[6]+r2[7] + b2[1];
}

extern "C" void kernel_launch(void* const* d_in, const int* in_sizes, int n_in,
                              void* d_out, int out_size, void* d_ws, size_t ws_size,
                              hipStream_t stream) {
  const float* x_node    = (const float*)d_in[0];
  const float* x_full    = (const float*)d_in[1];
  const float* Wp        = (const float*)d_in[2];
  const float* bp        = (const float*)d_in[3];
  const float* cls       = (const float*)d_in[4];
  const float* e_w1      = (const float*)d_in[5];
  const float* e_b1      = (const float*)d_in[6];
  const float* e_w2      = (const float*)d_in[7];
  const float* e_b2      = (const float*)d_in[8];
  const float* edge_scale= (const float*)d_in[9];
  const float* qkv_w     = (const float*)d_in[10];
  const float* qkv_b     = (const float*)d_in[11];
  const float* out_w     = (const float*)d_in[12];
  const float* out_b     = (const float*)d_in[13];
  const float* ln1_w     = (const float*)d_in[14];
  const float* ln1_b     = (const float*)d_in[15];
  const float* ln2_w     = (const float*)d_in[16];
  const float* ln2_b     = (const float*)d_in[17];
  const float* ff1_w     = (const float*)d_in[18];
  const float* ff1_b     = (const float*)d_in[19];
  const float* ff2_w     = (const float*)d_in[20];
  const float* ff2_b     = (const float*)d_in[21];
  const float* cl_ln_w   = (const float*)d_in[22];
  const float* cl_ln_b   = (const float*)d_in[23];
  const float* cl_w1     = (const float*)d_in[24];
  const float* cl_b1     = (const float*)d_in[25];
  const float* cl_w2     = (const float*)d_in[26];
  const float* cl_b2     = (const float*)d_in[27];
  float* out = (float*)d_out;

  char* w = (char*)d_ws;
  size_t off = 0;
  auto take = [&](size_t bytes)->char*{
    char* p = w + off;
    off += (bytes + 255) & ~(size_t)255;
    return p;
  };
  unsigned short* wq8   = (unsigned short*)take((size_t)LL*1536*512*2);
  unsigned short* wo8   = (unsigned short*)take((size_t)LL*512*512*2);
  unsigned short* wf1   = (unsigned short*)take((size_t)LL*2048*512*2);
  unsigned short* wf2   = (unsigned short*)take((size_t)LL*512*2048*2);
  unsigned short* bias16= (unsigned short*)take((size_t)BB*HH*SS*BSTR*2 + 65536); // pad: qt=8 stages rows past end
  float*          cent  = (float*)take((size_t)BB*NN*HH*4);
  float*          hbuf  = (float*)take((size_t)MPAD*DD*4);
  unsigned short* xb    = (unsigned short*)take((size_t)MPAD*DD*2);
  unsigned short* obuf  = (unsigned short*)take((size_t)MPAD*DD*2);
  unsigned short* qkvb  = (unsigned short*)take((size_t)MPAD*1536*2);
  unsigned short* vtb   = (unsigned short*)take((size_t)BB*HH*HDD*VSTR*2);
  unsigned short* ffb   = qkvb;   // union: FF intermediate reuses dead qkv+vt region

  // weights -> bf16
  cvt_kernel<<<4096, 256, 0, stream>>>(qkv_w, wq8, LL*1536*512/2);
  cvt_kernel<<<4096, 256, 0, stream>>>(out_w, wo8, LL*512*512/2);
  cvt_kernel<<<4096, 256, 0, stream>>>(ff1_w, wf1, LL*2048*512/2);
  cvt_kernel<<<4096, 256, 0, stream>>>(ff2_w, wf2, LL*512*2048/2);

  edge_kernel<<<dim3(BB*NN), 256, 0, stream>>>(x_full, e_w1, e_b1, e_w2, e_b2, bias16, cent);
  edge_border_kernel<<<dim3(BB*HH), 256, 0, stream>>>(cent, edge_scale, bias16);
  proj_kernel<<<dim3(MTOK), 256, 0, stream>>>(x_node, Wp, bp, cls, hbuf);

  for (int l = 0; l < LL; ++l){
    ln_kernel<<<dim3(MTOK/4), 256, 0, stream>>>(hbuf, ln1_w + l*DD, ln1_b + l*DD, xb);
    gemm_kernel<0,4,4,4><<<dim3(129*12), 256, 0, stream>>>(xb, wq8 + (size_t)l*1536*512,
        qkv_b + (size_t)l*1536, qkvb, MTOK, 1536, 512, 1536, 12);
    vtrans_kernel<<<dim3(512, 5), 256, 0, stream>>>(qkvb, vtb);
    flash_kernel<<<dim3(512), 576, 0, stream>>>(qkvb, vtb, bias16, obuf);
    gemm_kernel<2,4,2,6><<<dim3(129*8), 256, 0, stream>>>(obuf, wo8 + (size_t)l*512*512,
        out_b + (size_t)l*DD, hbuf, MTOK, 512, 512, 512, 8);
    ln_kernel<<<dim3(MTOK/4), 256, 0, stream>>>(hbuf, ln2_w + l*DD, ln2_b + l*DD, xb);
    gemm_kernel<1,4,4,4><<<dim3(129*16), 256, 0, stream>>>(xb, wf1 + (size_t)l*2048*512,
        ff1_b + (size_t)l*2048, ffb, MTOK, 2048, 512, 2048, 16);
    gemm_kernel<2,4,2,6><<<dim3(129*8), 256, 0, stream>>>(ffb, wf2 + (size_t)l*512*2048,
        ff2_b + (size_t)l*DD, hbuf, MTOK, 512, 2048, 512, 8);
  }
  cls_kernel<<<dim3(BB), 256, 0, stream>>>(hbuf, cl_ln_w, cl_ln_b, cl_w1, cl_b1, cl_w2, cl_b2, out);
}